// Round 13
// baseline (75.515 us; speedup 1.0000x reference)
//
#include <hip/hip_runtime.h>

#define B_ 8
#define DIM_ 512
#define HEADS_ 8
#define HD_ 64
#define HW_ 1024
#define L_ 77
#define LP_ 80
#define CTX_ 768
#define KV_ 1101
#define KVP_ 1152
#define NPAD_ 51
// internal KV order: self-attn rows [0,1024), context rows [1024,1101), pad [1101,1152)
#define CTX0_ 1024
// sqrt(SCALE^2 * log2(e)) folded into both q and k: 64^-0.25 * sqrt(1.4426950409)
#define SC_QK 0.42466089f

typedef __attribute__((ext_vector_type(8))) short bf16x8;
typedef __attribute__((ext_vector_type(4))) float f32x4;
typedef __attribute__((ext_vector_type(4))) unsigned short u16x4;

__device__ __forceinline__ unsigned short f2bf(float f) {
  union { float f; unsigned int u; } c; c.f = f;
  unsigned int u = c.u;
  return (unsigned short)((u + 0x7fffu + ((u >> 16) & 1u)) >> 16);
}
__device__ __forceinline__ float bf2f(unsigned short h) {
  union { unsigned int u; float f; } c; c.u = ((unsigned int)h) << 16;
  return c.f;
}

#define GLD_LDS16(gsrc, ldst) \
  __builtin_amdgcn_global_load_lds((const __attribute__((address_space(1))) void*)(gsrc), \
                                   (__attribute__((address_space(3))) void*)(ldst), 16, 0, 0)

// ---------------- prep: gnorm + weight converts + ctx convert + KV pad zero ----------------
__global__ __launch_bounds__(256) void prep_k(const float* __restrict__ x,
                                              const float* __restrict__ gamma,
                                              const float* __restrict__ beta,
                                              const float* __restrict__ qkv_w,
                                              const float* __restrict__ ckv_w,
                                              const float* __restrict__ proj_w,
                                              const float* __restrict__ ctx,
                                              unsigned short* __restrict__ xn_t,
                                              unsigned short* __restrict__ dq,
                                              unsigned short* __restrict__ dc,
                                              unsigned short* __restrict__ dp,
                                              unsigned short* __restrict__ ctx_bf,
                                              unsigned short* __restrict__ k_s,
                                              unsigned short* __restrict__ vT) {
  __shared__ unsigned short xs[16][1032];
  __shared__ float red[8];
  int bid = blockIdx.x;
  int tid = threadIdx.x;
  if (bid < 256) {
    // groupnorm: fused stats + normalize + transpose
    const int b = bid >> 5, g = bid & 31;
    const float* xp = x + ((size_t)b * DIM_ + g * 16) * HW_;
    float sum = 0.f, ssq = 0.f;
#pragma unroll
    for (int i = 0; i < 16; ++i) {
      float4 v = *(const float4*)&xp[i * HW_ + tid * 4];
      sum += v.x + v.y + v.z + v.w;
      ssq += v.x * v.x + v.y * v.y + v.z * v.z + v.w * v.w;
      xs[i][tid * 4 + 0] = f2bf(v.x);
      xs[i][tid * 4 + 1] = f2bf(v.y);
      xs[i][tid * 4 + 2] = f2bf(v.z);
      xs[i][tid * 4 + 3] = f2bf(v.w);
    }
#pragma unroll
    for (int off = 32; off >= 1; off >>= 1) {
      sum += __shfl_xor(sum, off, 64);
      ssq += __shfl_xor(ssq, off, 64);
    }
    if ((tid & 63) == 0) { red[(tid >> 6) * 2] = sum; red[(tid >> 6) * 2 + 1] = ssq; }
    __syncthreads();
    sum = red[0] + red[2] + red[4] + red[6];
    ssq = red[1] + red[3] + red[5] + red[7];
    float mu = sum * (1.f / 16384.f);
    float rstd = rsqrtf(ssq * (1.f / 16384.f) - mu * mu + 1e-5f);
    float a[16], c[16];
#pragma unroll
    for (int ci = 0; ci < 16; ++ci) {
      float gm = gamma[g * 16 + ci], bt = beta[g * 16 + ci];
      a[ci] = rstd * gm;
      c[ci] = bt - mu * rstd * gm;
    }
#pragma unroll
    for (int t = 0; t < 4; ++t) {
      int hw = tid + t * 256;
      unsigned short tmp[16];
#pragma unroll
      for (int ci = 0; ci < 16; ++ci)
        tmp[ci] = f2bf(bf2f(xs[ci][hw]) * a[ci] + c[ci]);
      unsigned int w[8];
#pragma unroll
      for (int j = 0; j < 8; ++j) w[j] = (unsigned int)tmp[2 * j] | ((unsigned int)tmp[2 * j + 1] << 16);
      unsigned short* dptr = &xn_t[((size_t)b * HW_ + hw) * DIM_ + g * 16];
      *(uint4*)dptr = make_uint4(w[0], w[1], w[2], w[3]);
      *(uint4*)(dptr + 8) = make_uint4(w[4], w[5], w[6], w[7]);
    }
  } else if (bid < 2048) {
    // f32->bf16 weight converts
    int i = (bid - 256) * 256 + tid;
    const float* src;
    unsigned short* dst;
    int off;
    if (i < 196608) { src = qkv_w; dst = dq; off = i; }                 // 3*512*512/4
    else if (i < 393216) { src = ckv_w; dst = dc; off = i - 196608; }   // 2*512*768/4
    else { src = proj_w; dst = dp; off = i - 393216; }                  // 512*512/4
    float4 v = *(const float4*)(src + (size_t)off * 4);
    u16x4 o;
    o[0] = f2bf(v.x); o[1] = f2bf(v.y); o[2] = f2bf(v.z); o[3] = f2bf(v.w);
    *(u16x4*)(dst + (size_t)off * 4) = o;
  } else if (bid < 2528) {
    // ctx f32 -> bf16, padded L_->LP_
    int i = (bid - 2048) * 256 + tid;
    int idx = i * 4;
    int b = idx / (LP_ * CTX_);
    int rem = idx - b * (LP_ * CTX_);
    int l = rem / CTX_;
    int c = rem - l * CTX_;
    float4 v = make_float4(0.f, 0.f, 0.f, 0.f);
    if (l < L_) v = *(const float4*)&ctx[((size_t)b * L_ + l) * CTX_ + c];
    u16x4 o;
    o[0] = f2bf(v.x); o[1] = f2bf(v.y); o[2] = f2bf(v.z); o[3] = f2bf(v.w);
    *(u16x4*)(ctx_bf + idx) = o;
  } else {
    // zero KV pad rows [KV_, KVP_) — K zeros make S_pad=0 -> P_pad=1 (corrected
    // by -NPAD_ in the attn denominator); V zeros keep the numerator exact.
    int i = (bid - 2528) * 256 + tid;
    int bh = i / (NPAD_ * 64);
    int rem = i - bh * (NPAD_ * 64);
    int row = KV_ + rem / 64;
    int d = rem & 63;
    k_s[((size_t)bh * KVP_ + row) * HD_ + d] = 0;
    vT[((size_t)bh * HD_ + d) * KVP_ + row] = 0;
  }
}

// ---------------- GEMM body: C[m][n] = sum_k A[m][k]*Bt[n][k] ----------------
// BK=32, TRIPLE-buffered LDS, ONE barrier per K-step (stage(kt+2) overwrites the
// buffer last read at kt-1; every wave crossing barrier(kt) has completed its
// kt-1 lgkm waits, so the overwrite is safe). Counted vmcnt keeps stage(kt+1)
// in flight across the barrier. XOR chunk swizzle: physical chunk p holds
// logical chunk p^((row>>1)&3) -> 2-way (free) LDS read pattern.
// MODE 0: qkv -> LDS-transpose epilogue, coalesced q/k/v stores (+bias, SC_QK)
// MODE 1: ckv -> scalar scatter to k_s/vT at rows 1024+l
// MODE 2: proj -> out = acc + bias[row] + x (residual), coalesced f32
template <int MODE, int BM, int BN>
__device__ __forceinline__ void gemm_body(int bid,
                                          const unsigned short* __restrict__ A,
                                          const unsigned short* __restrict__ Bt,
                                          int M, int N, int K,
                                          const float* __restrict__ bias,
                                          unsigned short* __restrict__ out_q,
                                          unsigned short* __restrict__ out_k,
                                          unsigned short* __restrict__ out_v,
                                          const float* __restrict__ xres,
                                          float* __restrict__ outf,
                                          unsigned short* sm) {
  constexpr int MR = BM / 32;
  constexpr int NR = BN / 32;
  constexpr int AG = BM / 64;            // per-thread A loads per stage
  constexpr int BG = BN / 64;
  constexpr int SLOADS = AG + BG;
  unsigned short* As0 = sm;              // [3][BM*32]
  unsigned short* Bs0 = sm + 3 * BM * 32;// [3][BN*32]
  const int tid = threadIdx.x;
  const int wid = tid >> 6, lane = tid & 63;
  const int lr = lane & 15, lg = lane >> 4;
  const int ntn = N / BN;
  const int tm = bid / ntn, tn = bid - tm * ntn;
  const int m0 = tm * BM, n0 = tn * BN;
  const int wr = wid >> 1, wc = wid & 1;
  f32x4 acc[MR][NR] = {};
  const int nkt = K >> 5;

  auto stage = [&](int bi, int kk) {
#pragma unroll
    for (int i = 0; i < AG; ++i) {
      int c = i * 256 + tid;
      int row = c >> 2, l = (c & 3) ^ ((row >> 1) & 3);
      GLD_LDS16(A + (size_t)(m0 + row) * K + kk + l * 8,
                As0 + (size_t)bi * BM * 32 + (size_t)c * 8);
    }
#pragma unroll
    for (int i = 0; i < BG; ++i) {
      int c = i * 256 + tid;
      int row = c >> 2, l = (c & 3) ^ ((row >> 1) & 3);
      GLD_LDS16(Bt + (size_t)(n0 + row) * K + kk + l * 8,
                Bs0 + (size_t)bi * BN * 32 + (size_t)c * 8);
    }
  };

  // prologue: pin issue order so the counted vmcnt is exact
  __builtin_amdgcn_sched_barrier(0);
  stage(0, 0);
  __builtin_amdgcn_sched_barrier(0);
  stage(1, 32);
  __builtin_amdgcn_sched_barrier(0);

  int cur = 0;
  for (int kt = 0; kt < nkt; ++kt) {
    // stage(kt) landed; stage(kt+1) stays in flight across the barrier
    if (kt < nkt - 1) {
      if constexpr (SLOADS == 4) asm volatile("s_waitcnt vmcnt(4)" ::: "memory");
      else                       asm volatile("s_waitcnt vmcnt(3)" ::: "memory");
    } else {
      asm volatile("s_waitcnt vmcnt(0)" ::: "memory");
    }
    __builtin_amdgcn_sched_barrier(0);
    __builtin_amdgcn_s_barrier();
    __builtin_amdgcn_sched_barrier(0);
    if (kt + 2 < nkt) stage(cur == 0 ? 2 : cur - 1, (kt + 2) << 5);
    const unsigned short* Ab = As0 + cur * BM * 32;
    const unsigned short* Bb = Bs0 + cur * BN * 32;
    bf16x8 af[MR], bf[NR];
#pragma unroll
    for (int mi = 0; mi < MR; ++mi) {
      int row = wr * (BM / 2) + mi * 16 + lr;
      af[mi] = *(const bf16x8*)&Ab[row * 32 + ((lg ^ ((row >> 1) & 3)) * 8)];
    }
#pragma unroll
    for (int nj = 0; nj < NR; ++nj) {
      int row = wc * (BN / 2) + nj * 16 + lr;
      bf[nj] = *(const bf16x8*)&Bb[row * 32 + ((lg ^ ((row >> 1) & 3)) * 8)];
    }
#pragma unroll
    for (int mi = 0; mi < MR; ++mi)
#pragma unroll
      for (int nj = 0; nj < NR; ++nj)
        acc[mi][nj] = __builtin_amdgcn_mfma_f32_16x16x32_bf16(af[mi], bf[nj], acc[mi][nj], 0, 0, 0);
    cur = (cur == 2) ? 0 : cur + 1;
  }

  if constexpr (MODE == 0) {
    __syncthreads();  // all waves done reading As/Bs before sm is reused
    const int which = n0 >> 9;         // uniform per block: 0=q 1=k 2=v
    const int bb = m0 >> 10;
    const int qibase = m0 & 1023;
    if (which == 2) {
      // transpose v through LDS: logical [col 128][qi-chunk 32] of uint2 (4 bf16)
      uint2* Vt = (uint2*)sm;
#pragma unroll
      for (int mi = 0; mi < MR; ++mi) {
#pragma unroll
        for (int nj = 0; nj < NR; ++nj) {
          int col = wc * 64 + nj * 16 + lr;
          float b = bias[n0 + col];
          unsigned int w0, w1;
          float v0 = acc[mi][nj][0] + b, v1 = acc[mi][nj][1] + b;
          float v2 = acc[mi][nj][2] + b, v3 = acc[mi][nj][3] + b;
          asm("v_cvt_pk_bf16_f32 %0, %1, %2" : "=v"(w0) : "v"(v0), "v"(v1));
          asm("v_cvt_pk_bf16_f32 %0, %1, %2" : "=v"(w1) : "v"(v2), "v"(v3));
          int chunk = (wr * 16 + mi * 4 + lg) ^ (lr * 2);
          Vt[col * 32 + chunk] = make_uint2(w0, w1);
        }
      }
      __syncthreads();
#pragma unroll
      for (int it = 0; it < 8; ++it) {
        int col = wid * 32 + it * 4 + lg;
        uint4 val = *(uint4*)&Vt[col * 32 + ((lr * 2) ^ ((col & 15) * 2))];
        int colg = n0 + col;
        int head = (colg >> 6) & 7, d = colg & 63;
        *(uint4*)&out_v[(((size_t)bb * HEADS_ + head) * HD_ + d) * KVP_ + qibase + lr * 8] = val;
      }
    } else {
      // q/k: [qi 128][col 128 (+4 pad)] in LDS, then coalesced 16B row stores
      unsigned short* Tq = sm;
#pragma unroll
      for (int mi = 0; mi < MR; ++mi) {
#pragma unroll
        for (int nj = 0; nj < NR; ++nj) {
          int col = wc * 64 + nj * 16 + lr;
          float b = bias[n0 + col];
          int qr = wr * 64 + mi * 16 + lg * 4;
#pragma unroll
          for (int r = 0; r < 4; ++r)
            Tq[(qr + r) * 132 + col] = f2bf((acc[mi][nj][r] + b) * SC_QK);
        }
      }
      __syncthreads();
#pragma unroll
      for (int it = 0; it < 8; ++it) {
        int qi = wid * 32 + it * 4 + lg;
        uint2 lo = *(uint2*)&Tq[qi * 132 + lr * 8];
        uint2 hi = *(uint2*)&Tq[qi * 132 + lr * 8 + 4];
        uint4 val = make_uint4(lo.x, lo.y, hi.x, hi.y);
        int colg = n0 + lr * 8;
        int head = (colg >> 6) & 7, d = colg & 63;
        size_t bh = (size_t)bb * HEADS_ + head;
        if (which == 0)
          *(uint4*)&out_q[(bh * HW_ + qibase + qi) * HD_ + d] = val;
        else
          *(uint4*)&out_k[(bh * KVP_ + qibase + qi) * HD_ + d] = val;
      }
    }
  } else {
#pragma unroll
    for (int mi = 0; mi < MR; ++mi) {
#pragma unroll
      for (int nj = 0; nj < NR; ++nj) {
#pragma unroll
        for (int r = 0; r < 4; ++r) {
          int row = m0 + wr * (BM / 2) + mi * 16 + lg * 4 + r;
          int col = n0 + wc * (BN / 2) + nj * 16 + lr;
          float v = acc[mi][nj][r];
          if (MODE == 1) {
            int bb = row / LP_, l = row - bb * LP_;
            if (l < L_) {
              v += bias[col];
              int which = col >> 9, head = (col >> 6) & 7, d = col & 63;
              size_t bh = (size_t)bb * HEADS_ + head;
              if (which == 0) out_k[(bh * KVP_ + CTX0_ + l) * HD_ + d] = f2bf(v * SC_QK);
              else            out_v[(bh * HD_ + d) * KVP_ + CTX0_ + l] = f2bf(v);
            }
          } else {
            size_t idx = (size_t)(col >> 10) * (DIM_ * HW_) + (size_t)row * HW_ + (col & 1023);
            outf[idx] = v + bias[row] + xres[idx];
          }
        }
      }
    }
  }
}

// fused ckv (blocks 0..79, 64x128 tiles, dispatched FIRST) + qkv (80..847, XCD-swizzled)
__global__ __launch_bounds__(256, 3) void gemm_qkv_ckv_k(
    const unsigned short* __restrict__ xn_t, const unsigned short* __restrict__ qkvw,
    const unsigned short* __restrict__ ctx_bf, const unsigned short* __restrict__ ckvw,
    const float* __restrict__ qkv_b, const float* __restrict__ ckv_b,
    unsigned short* __restrict__ q_s, unsigned short* __restrict__ k_s,
    unsigned short* __restrict__ vT) {
  __shared__ unsigned short sm[3 * 256 * 32];
  int bid = blockIdx.x;
  if (bid < 80) {
    gemm_body<1, 64, 128>(bid, ctx_bf, ckvw, 640, 1024, 768, ckv_b,
                          nullptr, k_s, vT, nullptr, nullptr, sm);
  } else {
    int b = bid - 80;
    int b2 = (b & 7) * 96 + (b >> 3);
    gemm_body<0, 128, 128>(b2, xn_t, qkvw, 8192, 1536, 512, qkv_b,
                           q_s, k_s, vT, nullptr, nullptr, sm);
  }
}

__global__ __launch_bounds__(256, 4) void gemm_proj_k(
    const unsigned short* __restrict__ projw, const unsigned short* __restrict__ at_s,
    const float* __restrict__ proj_b, const float* __restrict__ x,
    float* __restrict__ out) {
  __shared__ unsigned short sm[3 * 192 * 32];
  gemm_body<2, 64, 128>(blockIdx.x, projw, at_s, 512, 8192, 512, proj_b,
                        nullptr, nullptr, nullptr, x, out, sm);
}

// ---------------- flash attention: 4 waves x 2 q-cols, no-max softmax, MFMA row-sum ----------------
#define PSTRIDE 72

__device__ __forceinline__ void attn_tile64(const unsigned short* __restrict__ Ksb,
                                            const unsigned short* __restrict__ Vsb,
                                            const bf16x8 (&qf)[2][2], const bf16x8 ones,
                                            unsigned short* __restrict__ Pw0,
                                            unsigned short* __restrict__ Pw1,
                                            int lr, int lg,
                                            const int (&ro)[4], const int (&koff)[2],
                                            f32x4 (&lacc)[2], f32x4 (&acc)[2][4]) {
  f32x4 st[2][4] = {};
  __builtin_amdgcn_s_setprio(1);
#pragma unroll
  for (int ks = 0; ks < 2; ++ks) {
    bf16x8 kf[4];
#pragma unroll
    for (int t = 0; t < 4; ++t)
      kf[t] = *(const bf16x8*)&Ksb[ro[t] + koff[ks]];
#pragma unroll
    for (int t = 0; t < 4; ++t) {
      st[0][t] = __builtin_amdgcn_mfma_f32_16x16x32_bf16(kf[t], qf[0][ks], st[0][t], 0, 0, 0);
      st[1][t] = __builtin_amdgcn_mfma_f32_16x16x32_bf16(kf[t], qf[1][ks], st[1][t], 0, 0, 0);
    }
  }
  __builtin_amdgcn_s_setprio(0);
  // p = exp2(S), raw v_exp_f32 (inputs bounded)
#pragma unroll
  for (int c = 0; c < 2; ++c) {
#pragma unroll
    for (int t = 0; t < 4; ++t)
#pragma unroll
      for (int r = 0; r < 4; ++r) st[c][t][r] = __builtin_amdgcn_exp2f(st[c][t][r]);
    unsigned short* Pw = c ? Pw1 : Pw0;
#pragma unroll
    for (int t = 0; t < 4; ++t) {
      unsigned int w0, w1;
      asm("v_cvt_pk_bf16_f32 %0, %1, %2" : "=v"(w0) : "v"(st[c][t][0]), "v"(st[c][t][1]));
      asm("v_cvt_pk_bf16_f32 %0, %1, %2" : "=v"(w1) : "v"(st[c][t][2]), "v"(st[c][t][3]));
      *(uint2*)&Pw[lr * PSTRIDE + t * 16 + lg * 4] = make_uint2(w0, w1);
    }
  }
  // PV + row-sum; V fragments shared across both q-cols
#pragma unroll
  for (int ks = 0; ks < 2; ++ks) {
    bf16x8 pb0 = *(const bf16x8*)&Pw0[lr * PSTRIDE + ks * 32 + lg * 8];
    bf16x8 pb1 = *(const bf16x8*)&Pw1[lr * PSTRIDE + ks * 32 + lg * 8];
    __builtin_amdgcn_s_setprio(1);
    lacc[0] = __builtin_amdgcn_mfma_f32_16x16x32_bf16(ones, pb0, lacc[0], 0, 0, 0);
    lacc[1] = __builtin_amdgcn_mfma_f32_16x16x32_bf16(ones, pb1, lacc[1], 0, 0, 0);
#pragma unroll
    for (int dt = 0; dt < 4; ++dt) {
      bf16x8 vf = *(const bf16x8*)&Vsb[ro[dt] + koff[ks]];
      acc[0][dt] = __builtin_amdgcn_mfma_f32_16x16x32_bf16(vf, pb0, acc[0][dt], 0, 0, 0);
      acc[1][dt] = __builtin_amdgcn_mfma_f32_16x16x32_bf16(vf, pb1, acc[1][dt], 0, 0, 0);
    }
    __builtin_amdgcn_s_setprio(0);
  }
}

__global__ __launch_bounds__(256, 3) void attn_k(const unsigned short* __restrict__ q_s,
                                                 const unsigned short* __restrict__ k_s,
                                                 const unsigned short* __restrict__ vT,
                                                 unsigned short* __restrict__ at_s) {
  __shared__ unsigned short Ks[2][4096];
  __shared__ unsigned short Vs[2][4096];
  __shared__ unsigned short Pb[4][2][16 * PSTRIDE];
  const int tid = threadIdx.x;
  const int wid = tid >> 6, lane = tid & 63;
  const int lr = lane & 15, lg = lane >> 4;
  const int bidx = blockIdx.x;
  const int xcd = bidx & 7, idx = bidx >> 3;
  const int bh = xcd + 8 * (idx >> 3);
  const int qt = idx & 7;
  const int q0 = qt * 128 + wid * 32;   // two 16-q cols per wave
  const unsigned short* qp = q_s + (size_t)bh * HW_ * HD_;
  const unsigned short* kp = k_s + (size_t)bh * KVP_ * HD_;
  const unsigned short* vp = vT + (size_t)bh * HD_ * KVP_;
  unsigned short* Pw0 = Pb[wid][0];
  unsigned short* Pw1 = Pb[wid][1];

  const int srow = lane >> 3;
  const int schunk = (lane & 7) ^ srow;

  auto stage = [&](int bufi, int kk) {
#pragma unroll
    for (int jj = 0; jj < 2; ++jj) {
      GLD_LDS16(kp + (size_t)(kk + wid * 16 + jj * 8 + srow) * HD_ + schunk * 8,
                &Ks[bufi][(wid * 2 + jj) * 512]);
      GLD_LDS16(vp + (size_t)(wid * 16 + jj * 8 + srow) * KVP_ + kk + schunk * 8,
                &Vs[bufi][(wid * 2 + jj) * 512]);
    }
  };

  int ro[4], koff[2];
#pragma unroll
  for (int t = 0; t < 4; ++t) ro[t] = (t * 16 + lr) * 64;
#pragma unroll
  for (int ks = 0; ks < 2; ++ks) koff[ks] = ((ks * 4 + lg) ^ (lr & 7)) * 8;

  bf16x8 qf[2][2];
#pragma unroll
  for (int c = 0; c < 2; ++c)
#pragma unroll
    for (int ks = 0; ks < 2; ++ks)
      qf[c][ks] = *(const bf16x8*)&qp[(size_t)(q0 + c * 16 + lr) * HD_ + ks * 32 + lg * 8];

  bf16x8 ones;
#pragma unroll
  for (int j = 0; j < 8; ++j) ones[j] = (short)0x3F80;  // bf16 1.0

  f32x4 acc[2][4] = {};
  f32x4 lacc[2] = {};

  __builtin_amdgcn_sched_barrier(0);
  stage(0, 0);
  __builtin_amdgcn_sched_barrier(0);
  stage(1, 64);
  __builtin_amdgcn_sched_barrier(0);

  int cur = 0;
  for (int it = 0; it < 17; ++it) {
    asm volatile("s_waitcnt vmcnt(4)" ::: "memory");
    __builtin_amdgcn_sched_barrier(0);
    __builtin_amdgcn_s_barrier();
    __builtin_amdgcn_sched_barrier(0);
    attn_tile64(Ks[cur], Vs[cur], qf, ones, Pw0, Pw1, lr, lg, ro, koff, lacc, acc);
    asm volatile("s_waitcnt lgkmcnt(0)" ::: "memory");
    __builtin_amdgcn_sched_barrier(0);
    __builtin_amdgcn_s_barrier();
    __builtin_amdgcn_sched_barrier(0);
    if (it < 16) stage(cur, (it + 2) * 64);
    cur ^= 1;
  }
  asm volatile("s_waitcnt vmcnt(0)" ::: "memory");
  __builtin_amdgcn_sched_barrier(0);
  __builtin_amdgcn_s_barrier();
  __builtin_amdgcn_sched_barrier(0);
  attn_tile64(Ks[cur], Vs[cur], qf, ones, Pw0, Pw1, lr, lg, ro, koff, lacc, acc);

  const int bb = bh >> 3, head = bh & 7;
#pragma unroll
  for (int c = 0; c < 2; ++c) {
    const float inv = 1.f / (lacc[c][0] - (float)NPAD_);
    const int qi = q0 + c * 16 + lr;
#pragma unroll
    for (int dt = 0; dt < 4; ++dt) {
      u16x4 o;
#pragma unroll
      for (int r = 0; r < 4; ++r) o[r] = f2bf(acc[c][dt][r] * inv);
      *(u16x4*)&at_s[((size_t)bb * HW_ + qi) * DIM_ + head * HD_ + dt * 16 + lg * 4] = o;
    }
  }
}

extern "C" void kernel_launch(void* const* d_in, const int* in_sizes, int n_in,
                              void* d_out, int out_size, void* d_ws, size_t ws_size,
                              hipStream_t stream) {
  (void)in_sizes; (void)n_in; (void)out_size; (void)ws_size;
  const float* x      = (const float*)d_in[0];
  const float* ctx    = (const float*)d_in[1];
  const float* gng    = (const float*)d_in[2];
  const float* gnb    = (const float*)d_in[3];
  const float* qkv_w  = (const float*)d_in[4];
  const float* qkv_b  = (const float*)d_in[5];
  const float* ckv_w  = (const float*)d_in[6];
  const float* ckv_b  = (const float*)d_in[7];
  const float* proj_w = (const float*)d_in[8];
  const float* proj_b = (const float*)d_in[9];
  float* out = (float*)d_out;

  char* ws = (char*)d_ws;
  size_t off = 0;
  auto alloc = [&](size_t bytes) {
    char* p = ws + off;
    off = (off + bytes + 255) & ~(size_t)255;
    return p;
  };
  unsigned short* xn_t    = (unsigned short*)alloc((size_t)B_ * HW_ * DIM_ * 2);
  unsigned short* ctx_bf  = (unsigned short*)alloc((size_t)B_ * LP_ * CTX_ * 2);
  unsigned short* qkvw_bf = (unsigned short*)alloc((size_t)3 * DIM_ * DIM_ * 2);
  unsigned short* ckvw_bf = (unsigned short*)alloc((size_t)2 * DIM_ * CTX_ * 2);
  unsigned short* projw_bf= (unsigned short*)alloc((size_t)DIM_ * DIM_ * 2);
  unsigned short* q_s     = (unsigned short*)alloc((size_t)64 * HW_ * HD_ * 2);
  unsigned short* k_s     = (unsigned short*)alloc((size_t)64 * KVP_ * HD_ * 2);
  unsigned short* vT      = (unsigned short*)alloc((size_t)64 * HD_ * KVP_ * 2);
  unsigned short* at_s    = (unsigned short*)alloc((size_t)B_ * HW_ * DIM_ * 2);

  prep_k<<<3344, 256, 0, stream>>>(x, gng, gnb, qkv_w, ckv_w, proj_w, ctx,
                                   xn_t, qkvw_bf, ckvw_bf, projw_bf, ctx_bf, k_s, vT);
  gemm_qkv_ckv_k<<<848, 256, 0, stream>>>(xn_t, qkvw_bf, ctx_bf, ckvw_bf,
                                          qkv_b, ckv_b, q_s, k_s, vT);
  attn_k<<<512, 256, 0, stream>>>(q_s, k_s, vT, at_s);
  gemm_proj_k<<<512, 256, 0, stream>>>(projw_bf, at_s, proj_b, x, out);
}